// Round 9
// baseline (285.772 us; speedup 1.0000x reference)
//
#include <hip/hip_runtime.h>

#define NF 128
#define NH 64
#define NC 40
#define BSHIFT 10                 // bucket = dst >> 10  (1024 nodes/bucket)
#define NB 98                     // ceil(100000 / 1024)
#define BIN_T 8192                // edges per k_bin block

typedef __attribute__((ext_vector_type(8))) short short8;
typedef __attribute__((ext_vector_type(4))) float float4v;

__device__ __forceinline__ unsigned rotl32(unsigned v, int s) { return (v << s) | (v >> (32 - s)); }

__device__ __forceinline__ unsigned short f2bf(float f) {   // fp32 -> bf16 RNE
  unsigned u = __float_as_uint(f);
  return (unsigned short)((u + 0x7FFFu + ((u >> 16) & 1u)) >> 16);
}
__device__ __forceinline__ float bf2f(unsigned short b) {
  return __uint_as_float(((unsigned)b) << 16);
}

// threefry2x32, key(0,42), partitionable path: bits = x0^x1 of counter (0, idx).
__device__ __forceinline__ unsigned threefry_bits(unsigned idx) {
  const unsigned k0 = 0u, k1 = 42u;
  const unsigned k2x = 0u ^ 42u ^ 0x1BD11BDAu;
  unsigned x0 = 0u, x1 = idx;
  x0 += k0; x1 += k1;
  x0 += x1; x1 = rotl32(x1, 13); x1 ^= x0;
  x0 += x1; x1 = rotl32(x1, 15); x1 ^= x0;
  x0 += x1; x1 = rotl32(x1, 26); x1 ^= x0;
  x0 += x1; x1 = rotl32(x1, 6);  x1 ^= x0;
  x0 += k1; x1 += k2x + 1u;
  x0 += x1; x1 = rotl32(x1, 17); x1 ^= x0;
  x0 += x1; x1 = rotl32(x1, 29); x1 ^= x0;
  x0 += x1; x1 = rotl32(x1, 16); x1 ^= x0;
  x0 += x1; x1 = rotl32(x1, 24); x1 ^= x0;
  x0 += k2x; x1 += k0 + 2u;
  x0 += x1; x1 = rotl32(x1, 13); x1 ^= x0;
  x0 += x1; x1 = rotl32(x1, 15); x1 ^= x0;
  x0 += x1; x1 = rotl32(x1, 26); x1 ^= x0;
  x0 += x1; x1 = rotl32(x1, 6);  x1 ^= x0;
  x0 += k0; x1 += k1 + 3u;
  x0 += x1; x1 = rotl32(x1, 17); x1 ^= x0;
  x0 += x1; x1 = rotl32(x1, 29); x1 ^= x0;
  x0 += x1; x1 = rotl32(x1, 16); x1 ^= x0;
  x0 += x1; x1 = rotl32(x1, 24); x1 ^= x0;
  x0 += k1; x1 += k2x + 4u;
  x0 += x1; x1 = rotl32(x1, 13); x1 ^= x0;
  x0 += x1; x1 = rotl32(x1, 15); x1 ^= x0;
  x0 += x1; x1 = rotl32(x1, 26); x1 ^= x0;
  x0 += x1; x1 = rotl32(x1, 6);  x1 ^= x0;
  x0 += k2x; x1 += k0 + 5u;
  return x0 ^ x1;
}

// One-shot: W1 -> bf16 transposed [c][k]; W2 -> bf16 transposed padded [c<48][k<64].
__global__ __launch_bounds__(256) void k_prep(const float* __restrict__ W1, const float* __restrict__ W2,
                                              unsigned short* __restrict__ Wt1b, unsigned short* __restrict__ Wt2b) {
  int id = blockIdx.x * 256 + threadIdx.x;
  if (id < NF * NH) {
    int k = id >> 6, c = id & 63;
    Wt1b[c * NF + k] = f2bf(W1[id]);
  } else if (id < NF * NH + 48 * NH) {
    int id2 = id - NF * NH;
    int c = id2 >> 6, k = id2 & 63;
    Wt2b[c * NH + k] = (c < NC) ? f2bf(W2[k * NC + c]) : 0;
  }
}

__global__ __launch_bounds__(256) void k_bhist(const int* __restrict__ dst, int* __restrict__ bcnt, int nE) {
  __shared__ int h[NB];
  int t = threadIdx.x;
  if (t < NB) h[t] = 0;
  __syncthreads();
  int stride = gridDim.x * 256;
  for (int e = blockIdx.x * 256 + t; e < nE; e += stride)
    atomicAdd(&h[dst[e] >> BSHIFT], 1);
  __syncthreads();
  if (t < NB && h[t]) atomicAdd(&bcnt[t], h[t]);
}

__global__ __launch_bounds__(128) void k_bscan(const int* __restrict__ bcnt, int* __restrict__ bbase,
                                               int* __restrict__ gcur, int* __restrict__ rp, int n, int nE) {
  int t = threadIdx.x;
  int v = (t < NB) ? bcnt[t] : 0;
  __shared__ int sh[128];
  sh[t] = v; __syncthreads();
  for (int off = 1; off < 128; off <<= 1) {
    int u = (t >= off) ? sh[t - off] : 0; __syncthreads();
    sh[t] += u; __syncthreads();
  }
  int excl = sh[t] - v;
  if (t < NB) { bbase[t] = excl; gcur[t] = excl; }
  if (t == 0) { bbase[NB] = nE; rp[n] = nE; }
}

// Bin edges: packed word = (src<<10) | (dst & 1023).  src < 2^17, so fits 27 bits.
__global__ __launch_bounds__(256) void k_bin(const int* __restrict__ src, const int* __restrict__ dst,
                                             int* __restrict__ gcur, unsigned* __restrict__ binned, int nE) {
  __shared__ int h[NB];
  __shared__ int off[NB];
  int t = threadIdx.x;
  int b0 = blockIdx.x * BIN_T;
  int b1 = b0 + BIN_T; if (b1 > nE) b1 = nE;
  if (t < NB) h[t] = 0;
  __syncthreads();
  for (int e = b0 + t; e < b1; e += 256)
    atomicAdd(&h[dst[e] >> BSHIFT], 1);
  __syncthreads();
  if (t < NB && h[t] > 0) off[t] = atomicAdd(&gcur[t], h[t]);
  __syncthreads();
  for (int e = b0 + t; e < b1; e += 256) {
    int s = src[e], d = dst[e];
    int p = atomicAdd(&off[d >> BSHIFT], 1);
    binned[p] = ((unsigned)s << BSHIFT) | (unsigned)(d & ((1 << BSHIFT) - 1));
  }
}

__global__ __launch_bounds__(1024) void k_fillb(const unsigned* __restrict__ binned, const int* __restrict__ bbase,
                                                int* __restrict__ rp, float* __restrict__ dis,
                                                int* __restrict__ csrc, int n) {
  __shared__ int hist[1024];
  __shared__ int sbuf[1024];
  int b = blockIdx.x;
  int base = b << BSHIFT;
  int t = threadIdx.x;
  int lo = bbase[b], hi = bbase[b + 1];
  hist[t] = 0;
  __syncthreads();
  for (int e = lo + t; e < hi; e += 1024)
    atomicAdd(&hist[binned[e] & 1023u], 1);
  __syncthreads();
  int v = hist[t];
  sbuf[t] = v; __syncthreads();
  for (int off = 1; off < 1024; off <<= 1) {
    int u = (t >= off) ? sbuf[t - off] : 0; __syncthreads();
    sbuf[t] += u; __syncthreads();
  }
  int excl = sbuf[t] - v;
  if (base + t < n) {
    rp[base + t] = lo + excl;
    dis[base + t] = rsqrtf((float)(v + 1));
  }
  __syncthreads();
  hist[t] = lo + excl;
  __syncthreads();
  for (int e = lo + t; e < hi; e += 1024) {
    unsigned p = binned[e];
    int pos = atomicAdd(&hist[p & 1023u], 1);
    csrc[pos] = (int)(p >> BSHIFT);
  }
}

// y1 = bf16( dis[i] * (dropout(x) @ W1) ) via MFMA bf16.  16 nodes/block, 4 waves.
__global__ __launch_bounds__(256) void k_xw(const float* __restrict__ x, const unsigned short* __restrict__ Wt1b,
                                            const float* __restrict__ dis, unsigned short* __restrict__ y1b, int n) {
  __shared__ unsigned short Ws[NH * 136];
  __shared__ unsigned short xs[16 * 136];
  int t = threadIdx.x;
  int nodeBase = blockIdx.x * 16;
  for (int id = t; id < NH * 16; id += 256) {
    int c = id >> 4, kc = id & 15;
    *(short8*)&Ws[c * 136 + kc * 8] = *(const short8*)&Wt1b[c * NF + kc * 8];
  }
  {
    int nloc = t >> 4, kbase = (t & 15) * 8;
    int ebase = (nodeBase + nloc) * NF + kbase;
    const float4* xp = (const float4*)x;
    float4 a = xp[(ebase >> 2)];
    float4 b = xp[(ebase >> 2) + 1];
    float v[8] = {a.x, a.y, a.z, a.w, b.x, b.y, b.z, b.w};
#pragma unroll
    for (int q = 0; q < 8; ++q) {
      unsigned idx = (unsigned)(ebase + q);
      bool keep = (threefry_bits(idx) & 0x80000000u) == 0u;
      xs[nloc * 136 + kbase + q] = keep ? f2bf(v[q] * 2.0f) : 0;
    }
  }
  __syncthreads();
  int w = t >> 6, lane = t & 63;
  int m = lane & 15, quad = lane >> 4;
  float4v acc = {0.f, 0.f, 0.f, 0.f};
#pragma unroll
  for (int ks = 0; ks < 4; ++ks) {
    short8 a = *(const short8*)&xs[m * 136 + ks * 32 + quad * 8];
    short8 b = *(const short8*)&Ws[(w * 16 + m) * 136 + ks * 32 + quad * 8];
    acc = __builtin_amdgcn_mfma_f32_16x16x32_bf16(a, b, acc, 0, 0, 0);
  }
#pragma unroll
  for (int r = 0; r < 4; ++r) {
    int node = nodeBase + quad * 4 + r;
    y1b[node * NH + w * 16 + m] = f2bf(acc[r] * dis[node]);
  }
}

// g = bf16( dis[i] * relu( dis[i]*(sum y1[src] + y1[i]) + b1 ) ).
// Wave/node, lane=feature.  Edge indices read via wave-uniform (scalar) loads:
// readfirstlane(i) makes rp/csrc/base-addr chains SGPR-resident -> no bpermute,
// no vector csrc read, 3 VALU instrs per edge, 8 gathers in flight.
__global__ __launch_bounds__(256) void k_agg1(const unsigned short* __restrict__ y1b, const int* __restrict__ rp,
                                              const int* __restrict__ csrc, const float* __restrict__ dis,
                                              const float* __restrict__ b1, unsigned short* __restrict__ gb, int n) {
  int i = __builtin_amdgcn_readfirstlane(blockIdx.x * 4 + (threadIdx.x >> 6));
  if (i >= n) return;
  int lane = threadIdx.x & 63;
  float bias = b1[lane];
  float acc = bf2f(y1b[i * NH + lane]);
  float a0 = 0.f, a1 = 0.f, a2 = 0.f, a3 = 0.f, a4 = 0.f, a5 = 0.f, a6 = 0.f, a7 = 0.f;
  int lo = rp[i], hi = rp[i + 1];
  int e = lo;
  for (; e + 8 <= hi; e += 8) {
    int s0 = csrc[e + 0], s1 = csrc[e + 1], s2 = csrc[e + 2], s3 = csrc[e + 3];
    int s4 = csrc[e + 4], s5 = csrc[e + 5], s6 = csrc[e + 6], s7 = csrc[e + 7];
    float v0 = bf2f(y1b[s0 * NH + lane]), v1 = bf2f(y1b[s1 * NH + lane]);
    float v2 = bf2f(y1b[s2 * NH + lane]), v3 = bf2f(y1b[s3 * NH + lane]);
    float v4 = bf2f(y1b[s4 * NH + lane]), v5 = bf2f(y1b[s5 * NH + lane]);
    float v6 = bf2f(y1b[s6 * NH + lane]), v7 = bf2f(y1b[s7 * NH + lane]);
    a0 += v0; a1 += v1; a2 += v2; a3 += v3; a4 += v4; a5 += v5; a6 += v6; a7 += v7;
  }
  for (; e < hi; ++e) {
    int s = csrc[e];
    acc += bf2f(y1b[s * NH + lane]);
  }
  acc += ((a0 + a1) + (a2 + a3)) + ((a4 + a5) + (a6 + a7));
  float di = dis[i];
  float hval = fmaxf(fmaf(di, acc, bias), 0.f);
  gb[i * NH + lane] = f2bf(di * hval);
}

// ah = bf16( dis[i] * (sum g[src] + g[i]) ).  Same scalar-index gather structure.
__global__ __launch_bounds__(256) void k_aggg(const unsigned short* __restrict__ gb, const int* __restrict__ rp,
                                              const int* __restrict__ csrc, const float* __restrict__ dis,
                                              unsigned short* __restrict__ ahb, int n) {
  int i = __builtin_amdgcn_readfirstlane(blockIdx.x * 4 + (threadIdx.x >> 6));
  if (i >= n) return;
  int lane = threadIdx.x & 63;
  float acc = bf2f(gb[i * NH + lane]);
  float a0 = 0.f, a1 = 0.f, a2 = 0.f, a3 = 0.f, a4 = 0.f, a5 = 0.f, a6 = 0.f, a7 = 0.f;
  int lo = rp[i], hi = rp[i + 1];
  int e = lo;
  for (; e + 8 <= hi; e += 8) {
    int s0 = csrc[e + 0], s1 = csrc[e + 1], s2 = csrc[e + 2], s3 = csrc[e + 3];
    int s4 = csrc[e + 4], s5 = csrc[e + 5], s6 = csrc[e + 6], s7 = csrc[e + 7];
    float v0 = bf2f(gb[s0 * NH + lane]), v1 = bf2f(gb[s1 * NH + lane]);
    float v2 = bf2f(gb[s2 * NH + lane]), v3 = bf2f(gb[s3 * NH + lane]);
    float v4 = bf2f(gb[s4 * NH + lane]), v5 = bf2f(gb[s5 * NH + lane]);
    float v6 = bf2f(gb[s6 * NH + lane]), v7 = bf2f(gb[s7 * NH + lane]);
    a0 += v0; a1 += v1; a2 += v2; a3 += v3; a4 += v4; a5 += v5; a6 += v6; a7 += v7;
  }
  for (; e < hi; ++e) {
    int s = csrc[e];
    acc += bf2f(gb[s * NH + lane]);
  }
  acc += ((a0 + a1) + (a2 + a3)) + ((a4 + a5) + (a6 + a7));
  ahb[i * NH + lane] = f2bf(dis[i] * acc);
}

// out = ah @ W2 + b2  (fp32 out, direct).  16 nodes/block, 3 waves (48 padded cols).
__global__ __launch_bounds__(192) void k_hw2(const unsigned short* __restrict__ ahb, const unsigned short* __restrict__ Wt2b,
                                             const float* __restrict__ b2, float* __restrict__ out, int n) {
  __shared__ unsigned short Ws[48 * 72];
  __shared__ unsigned short xs[16 * 72];
  int t = threadIdx.x;
  int nodeBase = blockIdx.x * 16;
  for (int id = t; id < 48 * 8; id += 192) {
    int c = id >> 3, kc = id & 7;
    *(short8*)&Ws[c * 72 + kc * 8] = *(const short8*)&Wt2b[c * NH + kc * 8];
  }
  if (t < 128) {
    int c = t >> 3, kc = t & 7;
    *(short8*)&xs[c * 72 + kc * 8] = *(const short8*)&ahb[(nodeBase + c) * NH + kc * 8];
  }
  __syncthreads();
  int w = t >> 6, lane = t & 63;
  int m = lane & 15, quad = lane >> 4;
  float4v acc = {0.f, 0.f, 0.f, 0.f};
#pragma unroll
  for (int ks = 0; ks < 2; ++ks) {
    short8 a = *(const short8*)&xs[m * 72 + ks * 32 + quad * 8];
    short8 b = *(const short8*)&Ws[(w * 16 + m) * 72 + ks * 32 + quad * 8];
    acc = __builtin_amdgcn_mfma_f32_16x16x32_bf16(a, b, acc, 0, 0, 0);
  }
  int col = w * 16 + m;
  if (col < NC) {
    float bias = b2[col];
#pragma unroll
    for (int r = 0; r < 4; ++r) {
      int node = nodeBase + quad * 4 + r;
      out[node * NC + col] = acc[r] + bias;
    }
  }
}

extern "C" void kernel_launch(void* const* d_in, const int* in_sizes, int n_in,
                              void* d_out, int out_size, void* d_ws, size_t ws_size,
                              hipStream_t stream) {
  const float* x  = (const float*)d_in[0];
  const int*   ei = (const int*)d_in[1];
  const float* W1 = (const float*)d_in[2];
  const float* b1 = (const float*)d_in[3];
  const float* W2 = (const float*)d_in[4];
  const float* b2 = (const float*)d_in[5];
  float* out = (float*)d_out;
  int n  = in_sizes[0] / NF;    // 100000
  int nE = in_sizes[1] / 2;     // 1600000
  const int* src = ei;
  const int* dst = ei + nE;

  char* ws = (char*)d_ws;
  float* dis   = (float*)(ws + 0);                    // 400 KB
  int*   rp    = (int*)(ws + 400000);                 // n+1 ints
  int*   bcnt  = (int*)(ws + 800128);
  int*   bbase = (int*)(ws + 800640);
  int*   gcur  = (int*)(ws + 801152);
  unsigned short* Wt1b = (unsigned short*)(ws + 801664);   // 16 KB
  unsigned short* Wt2b = (unsigned short*)(ws + 818048);   // 6 KB
  int*   csrc  = (int*)(ws + 824192);                 // 6.4 MB
  unsigned short* y1b = (unsigned short*)(ws + 7224192);   // 12.8 MB (reused as ahb)
  unsigned short* gb  = (unsigned short*)(ws + 20024192);  // 12.8 MB
  unsigned* binned = (unsigned*)(ws + 20024192);      // 6.4 MB, overlays gb (dead before agg1)
  unsigned short* ahb = y1b;                          // y1 dead after agg1

  hipMemsetAsync(bcnt, 0, NB * 4, stream);

  k_prep <<<(NF * NH + 48 * NH + 255) / 256, 256, 0, stream>>>(W1, W2, Wt1b, Wt2b);
  k_bhist<<<512, 256, 0, stream>>>(dst, bcnt, nE);
  k_bscan<<<1, 128, 0, stream>>>(bcnt, bbase, gcur, rp, n, nE);
  k_bin  <<<(nE + BIN_T - 1) / BIN_T, 256, 0, stream>>>(src, dst, gcur, binned, nE);
  k_fillb<<<NB, 1024, 0, stream>>>(binned, bbase, rp, dis, csrc, n);
  k_xw   <<<n / 16, 256, 0, stream>>>(x, Wt1b, dis, y1b, n);
  k_agg1 <<<(n + 3) / 4, 256, 0, stream>>>(y1b, rp, csrc, dis, b1, gb, n);
  k_aggg <<<(n + 3) / 4, 256, 0, stream>>>(gb, rp, csrc, dis, ahb, n);
  k_hw2  <<<n / 16, 192, 0, stream>>>(ahb, Wt2b, b2, out, n);
}

// Round 12
// 279.877 us; speedup vs baseline: 1.0211x; 1.0211x over previous
//
#include <hip/hip_runtime.h>

#define NF 128
#define NH 64
#define NC 40
#define BSHIFT 10                 // bucket = dst >> 10  (1024 nodes/bucket)
#define NB 98                     // ceil(100000 / 1024)
#define BIN_T 8192                // edges per k_bin block

typedef __attribute__((ext_vector_type(8))) short short8;
typedef __attribute__((ext_vector_type(4))) float float4v;

__device__ __forceinline__ unsigned rotl32(unsigned v, int s) { return (v << s) | (v >> (32 - s)); }

__device__ __forceinline__ unsigned short f2bf(float f) {   // fp32 -> bf16 RNE
  unsigned u = __float_as_uint(f);
  return (unsigned short)((u + 0x7FFFu + ((u >> 16) & 1u)) >> 16);
}
__device__ __forceinline__ float bf2f(unsigned short b) {
  return __uint_as_float(((unsigned)b) << 16);
}
__device__ __forceinline__ float bfl(unsigned u) { return __uint_as_float(u << 16); }          // low bf16
__device__ __forceinline__ float bfh(unsigned u) { return __uint_as_float(u & 0xFFFF0000u); }  // high bf16

// threefry2x32, key(0,42), partitionable path: bits = x0^x1 of counter (0, idx).
__device__ __forceinline__ unsigned threefry_bits(unsigned idx) {
  const unsigned k0 = 0u, k1 = 42u;
  const unsigned k2x = 0u ^ 42u ^ 0x1BD11BDAu;
  unsigned x0 = 0u, x1 = idx;
  x0 += k0; x1 += k1;
  x0 += x1; x1 = rotl32(x1, 13); x1 ^= x0;
  x0 += x1; x1 = rotl32(x1, 15); x1 ^= x0;
  x0 += x1; x1 = rotl32(x1, 26); x1 ^= x0;
  x0 += x1; x1 = rotl32(x1, 6);  x1 ^= x0;
  x0 += k1; x1 += k2x + 1u;
  x0 += x1; x1 = rotl32(x1, 17); x1 ^= x0;
  x0 += x1; x1 = rotl32(x1, 29); x1 ^= x0;
  x0 += x1; x1 = rotl32(x1, 16); x1 ^= x0;
  x0 += x1; x1 = rotl32(x1, 24); x1 ^= x0;
  x0 += k2x; x1 += k0 + 2u;
  x0 += x1; x1 = rotl32(x1, 13); x1 ^= x0;
  x0 += x1; x1 = rotl32(x1, 15); x1 ^= x0;
  x0 += x1; x1 = rotl32(x1, 26); x1 ^= x0;
  x0 += x1; x1 = rotl32(x1, 6);  x1 ^= x0;
  x0 += k0; x1 += k1 + 3u;
  x0 += x1; x1 = rotl32(x1, 17); x1 ^= x0;
  x0 += x1; x1 = rotl32(x1, 29); x1 ^= x0;
  x0 += x1; x1 = rotl32(x1, 16); x1 ^= x0;
  x0 += x1; x1 = rotl32(x1, 24); x1 ^= x0;
  x0 += k1; x1 += k2x + 4u;
  x0 += x1; x1 = rotl32(x1, 13); x1 ^= x0;
  x0 += x1; x1 = rotl32(x1, 15); x1 ^= x0;
  x0 += x1; x1 = rotl32(x1, 26); x1 ^= x0;
  x0 += x1; x1 = rotl32(x1, 6);  x1 ^= x0;
  x0 += k2x; x1 += k0 + 5u;
  return x0 ^ x1;
}

// One-shot: W1/W2 -> bf16 transposed; also zero the sentinel rows n of y1b/gb.
__global__ __launch_bounds__(256) void k_prep(const float* __restrict__ W1, const float* __restrict__ W2,
                                              unsigned short* __restrict__ Wt1b, unsigned short* __restrict__ Wt2b,
                                              unsigned short* __restrict__ y1b, unsigned short* __restrict__ gb, int n) {
  int id = blockIdx.x * 256 + threadIdx.x;
  if (id < NF * NH) {
    int k = id >> 6, c = id & 63;
    Wt1b[c * NF + k] = f2bf(W1[id]);
  } else if (id < NF * NH + 48 * NH) {
    int id2 = id - NF * NH;
    int c = id2 >> 6, k = id2 & 63;
    Wt2b[c * NH + k] = (c < NC) ? f2bf(W2[k * NC + c]) : 0;
  } else if (id < NF * NH + 48 * NH + NH) {
    int k = id - (NF * NH + 48 * NH);
    y1b[n * NH + k] = 0;      // sentinel zero rows for masked tail gathers
    gb[n * NH + k] = 0;
  }
}

__global__ __launch_bounds__(256) void k_bhist(const int* __restrict__ dst, int* __restrict__ bcnt, int nE) {
  __shared__ int h[NB];
  int t = threadIdx.x;
  if (t < NB) h[t] = 0;
  __syncthreads();
  int stride = gridDim.x * 256;
  for (int e = blockIdx.x * 256 + t; e < nE; e += stride)
    atomicAdd(&h[dst[e] >> BSHIFT], 1);
  __syncthreads();
  if (t < NB && h[t]) atomicAdd(&bcnt[t], h[t]);
}

__global__ __launch_bounds__(128) void k_bscan(const int* __restrict__ bcnt, int* __restrict__ bbase,
                                               int* __restrict__ gcur, int* __restrict__ rp, int n, int nE) {
  int t = threadIdx.x;
  int v = (t < NB) ? bcnt[t] : 0;
  __shared__ int sh[128];
  sh[t] = v; __syncthreads();
  for (int off = 1; off < 128; off <<= 1) {
    int u = (t >= off) ? sh[t - off] : 0; __syncthreads();
    sh[t] += u; __syncthreads();
  }
  int excl = sh[t] - v;
  if (t < NB) { bbase[t] = excl; gcur[t] = excl; }
  if (t == 0) { bbase[NB] = nE; rp[n] = nE; }
}

// Bin edges: packed word = (src<<10) | (dst & 1023).  src < 2^17, so fits 27 bits.
__global__ __launch_bounds__(256) void k_bin(const int* __restrict__ src, const int* __restrict__ dst,
                                             int* __restrict__ gcur, unsigned* __restrict__ binned, int nE) {
  __shared__ int h[NB];
  __shared__ int off[NB];
  int t = threadIdx.x;
  int b0 = blockIdx.x * BIN_T;
  int b1 = b0 + BIN_T; if (b1 > nE) b1 = nE;
  if (t < NB) h[t] = 0;
  __syncthreads();
  for (int e = b0 + t; e < b1; e += 256)
    atomicAdd(&h[dst[e] >> BSHIFT], 1);
  __syncthreads();
  if (t < NB && h[t] > 0) off[t] = atomicAdd(&gcur[t], h[t]);
  __syncthreads();
  for (int e = b0 + t; e < b1; e += 256) {
    int s = src[e], d = dst[e];
    int p = atomicAdd(&off[d >> BSHIFT], 1);
    binned[p] = ((unsigned)s << BSHIFT) | (unsigned)(d & ((1 << BSHIFT) - 1));
  }
}

__global__ __launch_bounds__(1024) void k_fillb(const unsigned* __restrict__ binned, const int* __restrict__ bbase,
                                                int* __restrict__ rp, float* __restrict__ dis,
                                                int* __restrict__ csrc, int n) {
  __shared__ int hist[1024];
  __shared__ int sbuf[1024];
  int b = blockIdx.x;
  int base = b << BSHIFT;
  int t = threadIdx.x;
  int lo = bbase[b], hi = bbase[b + 1];
  hist[t] = 0;
  __syncthreads();
  for (int e = lo + t; e < hi; e += 1024)
    atomicAdd(&hist[binned[e] & 1023u], 1);
  __syncthreads();
  int v = hist[t];
  sbuf[t] = v; __syncthreads();
  for (int off = 1; off < 1024; off <<= 1) {
    int u = (t >= off) ? sbuf[t - off] : 0; __syncthreads();
    sbuf[t] += u; __syncthreads();
  }
  int excl = sbuf[t] - v;
  if (base + t < n) {
    rp[base + t] = lo + excl;
    dis[base + t] = rsqrtf((float)(v + 1));
  }
  __syncthreads();
  hist[t] = lo + excl;
  __syncthreads();
  for (int e = lo + t; e < hi; e += 1024) {
    unsigned p = binned[e];
    int pos = atomicAdd(&hist[p & 1023u], 1);
    csrc[pos] = (int)(p >> BSHIFT);
  }
}

// y1 = bf16( dis[i] * (dropout(x) @ W1) ) via MFMA bf16.  16 nodes/block, 4 waves.
__global__ __launch_bounds__(256) void k_xw(const float* __restrict__ x, const unsigned short* __restrict__ Wt1b,
                                            const float* __restrict__ dis, unsigned short* __restrict__ y1b, int n) {
  __shared__ unsigned short Ws[NH * 136];
  __shared__ unsigned short xs[16 * 136];
  int t = threadIdx.x;
  int nodeBase = blockIdx.x * 16;
  for (int id = t; id < NH * 16; id += 256) {
    int c = id >> 4, kc = id & 15;
    *(short8*)&Ws[c * 136 + kc * 8] = *(const short8*)&Wt1b[c * NF + kc * 8];
  }
  {
    int nloc = t >> 4, kbase = (t & 15) * 8;
    int ebase = (nodeBase + nloc) * NF + kbase;
    const float4* xp = (const float4*)x;
    float4 a = xp[(ebase >> 2)];
    float4 b = xp[(ebase >> 2) + 1];
    float v[8] = {a.x, a.y, a.z, a.w, b.x, b.y, b.z, b.w};
#pragma unroll
    for (int q = 0; q < 8; ++q) {
      unsigned idx = (unsigned)(ebase + q);
      bool keep = (threefry_bits(idx) & 0x80000000u) == 0u;
      xs[nloc * 136 + kbase + q] = keep ? f2bf(v[q] * 2.0f) : 0;
    }
  }
  __syncthreads();
  int w = t >> 6, lane = t & 63;
  int m = lane & 15, quad = lane >> 4;
  float4v acc = {0.f, 0.f, 0.f, 0.f};
#pragma unroll
  for (int ks = 0; ks < 4; ++ks) {
    short8 a = *(const short8*)&xs[m * 136 + ks * 32 + quad * 8];
    short8 b = *(const short8*)&Ws[(w * 16 + m) * 136 + ks * 32 + quad * 8];
    acc = __builtin_amdgcn_mfma_f32_16x16x32_bf16(a, b, acc, 0, 0, 0);
  }
#pragma unroll
  for (int r = 0; r < 4; ++r) {
    int node = nodeBase + quad * 4 + r;
    y1b[node * NH + w * 16 + m] = f2bf(acc[r] * dis[node]);
  }
}

// g = bf16( dis[i]*relu( dis[i]*(sum y1[src] + y1[i]) + b1 ) ).
// Wave/node.  Lane = (edge-slot r=l>>3, feature-oct o=l&7): lane reads its own
// csrc[e0+r] (8 consecutive dwords, 8x-replicated -> one coalesced VMEM instr),
// then one dwordx4 gather fetches 8 full 128-B rows = 8 edges per gather instr
// (gather pipe is per-instruction-bound ~19cy/instr — R4/R5/R9 evidence).
// Tail slots gather sentinel zero-row n.  3-round shfl_xor combines subsets.
__global__ __launch_bounds__(256) void k_agg1(const unsigned short* __restrict__ y1b, const int* __restrict__ rp,
                                              const int* __restrict__ csrc, const float* __restrict__ dis,
                                              const float* __restrict__ b1, unsigned short* __restrict__ gb, int n) {
  int i = __builtin_amdgcn_readfirstlane(blockIdx.x * 4 + (threadIdx.x >> 6));
  if (i >= n) return;
  int lane = threadIdx.x & 63;
  int r = lane >> 3, o = lane & 7;
  float a0 = 0.f, a1 = 0.f, a2 = 0.f, a3 = 0.f, a4 = 0.f, a5 = 0.f, a6 = 0.f, a7 = 0.f;
  int lo = rp[i], hi = rp[i + 1];
  for (int e0 = lo; e0 < hi; e0 += 8) {
    int e = e0 + r;
    int s = (e < hi) ? csrc[e] : n;
    uint4 u = *(const uint4*)&y1b[s * NH + o * 8];
    a0 += bfl(u.x); a1 += bfh(u.x); a2 += bfl(u.y); a3 += bfh(u.y);
    a4 += bfl(u.z); a5 += bfh(u.z); a6 += bfl(u.w); a7 += bfh(u.w);
  }
  float a[8] = {a0, a1, a2, a3, a4, a5, a6, a7};
#pragma unroll
  for (int k = 0; k < 8; ++k) {
    a[k] += __shfl_xor(a[k], 8);
    a[k] += __shfl_xor(a[k], 16);
    a[k] += __shfl_xor(a[k], 32);
  }
  uint4 su = *(const uint4*)&y1b[i * NH + o * 8];   // self row (added once, post-combine)
  a[0] += bfl(su.x); a[1] += bfh(su.x); a[2] += bfl(su.y); a[3] += bfh(su.y);
  a[4] += bfl(su.z); a[5] += bfh(su.z); a[6] += bfl(su.w); a[7] += bfh(su.w);
  float4 bA = *(const float4*)&b1[o * 8];
  float4 bB = *(const float4*)&b1[o * 8 + 4];
  float bias[8] = {bA.x, bA.y, bA.z, bA.w, bB.x, bB.y, bB.z, bB.w};
  float di = dis[i];
  unsigned short gv[8];
#pragma unroll
  for (int k = 0; k < 8; ++k)
    gv[k] = f2bf(di * fmaxf(fmaf(di, a[k], bias[k]), 0.f));
  if (r == 0) {
    uint4 w;
    w.x = (unsigned)gv[0] | ((unsigned)gv[1] << 16);
    w.y = (unsigned)gv[2] | ((unsigned)gv[3] << 16);
    w.z = (unsigned)gv[4] | ((unsigned)gv[5] << 16);
    w.w = (unsigned)gv[6] | ((unsigned)gv[7] << 16);
    *(uint4*)&gb[i * NH + o * 8] = w;
  }
}

// ah = bf16( dis[i] * (sum g[src] + g[i]) ).  Same 8-row-per-instruction gather.
__global__ __launch_bounds__(256) void k_aggg(const unsigned short* __restrict__ gb, const int* __restrict__ rp,
                                              const int* __restrict__ csrc, const float* __restrict__ dis,
                                              unsigned short* __restrict__ ahb, int n) {
  int i = __builtin_amdgcn_readfirstlane(blockIdx.x * 4 + (threadIdx.x >> 6));
  if (i >= n) return;
  int lane = threadIdx.x & 63;
  int r = lane >> 3, o = lane & 7;
  float a0 = 0.f, a1 = 0.f, a2 = 0.f, a3 = 0.f, a4 = 0.f, a5 = 0.f, a6 = 0.f, a7 = 0.f;
  int lo = rp[i], hi = rp[i + 1];
  for (int e0 = lo; e0 < hi; e0 += 8) {
    int e = e0 + r;
    int s = (e < hi) ? csrc[e] : n;
    uint4 u = *(const uint4*)&gb[s * NH + o * 8];
    a0 += bfl(u.x); a1 += bfh(u.x); a2 += bfl(u.y); a3 += bfh(u.y);
    a4 += bfl(u.z); a5 += bfh(u.z); a6 += bfl(u.w); a7 += bfh(u.w);
  }
  float a[8] = {a0, a1, a2, a3, a4, a5, a6, a7};
#pragma unroll
  for (int k = 0; k < 8; ++k) {
    a[k] += __shfl_xor(a[k], 8);
    a[k] += __shfl_xor(a[k], 16);
    a[k] += __shfl_xor(a[k], 32);
  }
  uint4 su = *(const uint4*)&gb[i * NH + o * 8];
  a[0] += bfl(su.x); a[1] += bfh(su.x); a[2] += bfl(su.y); a[3] += bfh(su.y);
  a[4] += bfl(su.z); a[5] += bfh(su.z); a[6] += bfl(su.w); a[7] += bfh(su.w);
  float di = dis[i];
  if (r == 0) {
    uint4 w;
    w.x = (unsigned)f2bf(di * a[0]) | ((unsigned)f2bf(di * a[1]) << 16);
    w.y = (unsigned)f2bf(di * a[2]) | ((unsigned)f2bf(di * a[3]) << 16);
    w.z = (unsigned)f2bf(di * a[4]) | ((unsigned)f2bf(di * a[5]) << 16);
    w.w = (unsigned)f2bf(di * a[6]) | ((unsigned)f2bf(di * a[7]) << 16);
    *(uint4*)&ahb[i * NH + o * 8] = w;
  }
}

// out = ah @ W2 + b2  (fp32 out, direct).  16 nodes/block, 3 waves (48 padded cols).
__global__ __launch_bounds__(192) void k_hw2(const unsigned short* __restrict__ ahb, const unsigned short* __restrict__ Wt2b,
                                             const float* __restrict__ b2, float* __restrict__ out, int n) {
  __shared__ unsigned short Ws[48 * 72];
  __shared__ unsigned short xs[16 * 72];
  int t = threadIdx.x;
  int nodeBase = blockIdx.x * 16;
  for (int id = t; id < 48 * 8; id += 192) {
    int c = id >> 3, kc = id & 7;
    *(short8*)&Ws[c * 72 + kc * 8] = *(const short8*)&Wt2b[c * NH + kc * 8];
  }
  if (t < 128) {
    int c = t >> 3, kc = t & 7;
    *(short8*)&xs[c * 72 + kc * 8] = *(const short8*)&ahb[(nodeBase + c) * NH + kc * 8];
  }
  __syncthreads();
  int w = t >> 6, lane = t & 63;
  int m = lane & 15, quad = lane >> 4;
  float4v acc = {0.f, 0.f, 0.f, 0.f};
#pragma unroll
  for (int ks = 0; ks < 2; ++ks) {
    short8 a = *(const short8*)&xs[m * 72 + ks * 32 + quad * 8];
    short8 b = *(const short8*)&Ws[(w * 16 + m) * 72 + ks * 32 + quad * 8];
    acc = __builtin_amdgcn_mfma_f32_16x16x32_bf16(a, b, acc, 0, 0, 0);
  }
  int col = w * 16 + m;
  if (col < NC) {
    float bias = b2[col];
#pragma unroll
    for (int r = 0; r < 4; ++r) {
      int node = nodeBase + quad * 4 + r;
      out[node * NC + col] = acc[r] + bias;
    }
  }
}

extern "C" void kernel_launch(void* const* d_in, const int* in_sizes, int n_in,
                              void* d_out, int out_size, void* d_ws, size_t ws_size,
                              hipStream_t stream) {
  const float* x  = (const float*)d_in[0];
  const int*   ei = (const int*)d_in[1];
  const float* W1 = (const float*)d_in[2];
  const float* b1 = (const float*)d_in[3];
  const float* W2 = (const float*)d_in[4];
  const float* b2 = (const float*)d_in[5];
  float* out = (float*)d_out;
  int n  = in_sizes[0] / NF;    // 100000
  int nE = in_sizes[1] / 2;     // 1600000
  const int* src = ei;
  const int* dst = ei + nE;

  char* ws = (char*)d_ws;
  float* dis   = (float*)(ws + 0);                    // 400 KB
  int*   rp    = (int*)(ws + 400000);                 // n+1 ints
  int*   bcnt  = (int*)(ws + 800128);
  int*   bbase = (int*)(ws + 800640);
  int*   gcur  = (int*)(ws + 801152);
  unsigned short* Wt1b = (unsigned short*)(ws + 801664);   // 16 KB
  unsigned short* Wt2b = (unsigned short*)(ws + 818048);   // 6 KB
  int*   csrc  = (int*)(ws + 824192);                 // 6.4 MB
  unsigned short* y1b = (unsigned short*)(ws + 7224192);   // 12.8 MB + sentinel row (reused as ahb)
  unsigned short* gb  = (unsigned short*)(ws + 20024320);  // 12.8 MB + sentinel row
  unsigned* binned = (unsigned*)(ws + 20024320);      // 6.4 MB, overlays gb rows (dead before agg1; gb sentinel at +12.8 MB untouched)
  unsigned short* ahb = y1b;                          // y1 dead after agg1

  hipMemsetAsync(bcnt, 0, NB * 4, stream);

  k_prep <<<(NF * NH + 48 * NH + NH + 255) / 256, 256, 0, stream>>>(W1, W2, Wt1b, Wt2b, y1b, gb, n);
  k_bhist<<<512, 256, 0, stream>>>(dst, bcnt, nE);
  k_bscan<<<1, 128, 0, stream>>>(bcnt, bbase, gcur, rp, n, nE);
  k_bin  <<<(nE + BIN_T - 1) / BIN_T, 256, 0, stream>>>(src, dst, gcur, binned, nE);
  k_fillb<<<NB, 1024, 0, stream>>>(binned, bbase, rp, dis, csrc, n);
  k_xw   <<<n / 16, 256, 0, stream>>>(x, Wt1b, dis, y1b, n);
  k_agg1 <<<(n + 3) / 4, 256, 0, stream>>>(y1b, rp, csrc, dis, b1, gb, n);
  k_aggg <<<(n + 3) / 4, 256, 0, stream>>>(gb, rp, csrc, dis, ahb, n);
  k_hw2  <<<n / 16, 192, 0, stream>>>(ahb, Wt2b, b2, out, n);
}